// Round 1
// baseline (208.354 us; speedup 1.0000x reference)
//
#include <hip/hip_runtime.h>
#include <math.h>

// Problem constants (x: [32, 256, 56, 56] fp32)
#define B_    32
#define C_    256
#define H_    56
#define W_    56
#define HW_   (H_ * W_)        // 3136
#define BHW_  (B_ * HW_)       // 100352
#define HW4_  (HW_ / 4)        // 784 float4 per (b,c) plane
#define NF4_  (BHW_ / 4)       // 25088 global float4 positions
#define GRID_ 784              // 32 f4 per block (exact: 784*32 = 25088)
#define CHUNKF4_ (NF4_ / GRID_)  // 32 float4 per block
#define POSPB_  (BHW_ / GRID_)   // 128 float positions per block

typedef float f4v __attribute__((ext_vector_type(4)));

// ---------------------------------------------------------------------------
// Kernel 1: channel-wise mean + max -> pool [B, 2, HW].
// 784 blocks x 512 threads, __launch_bounds__(512,6) -> 3 blocks/CU resident
// = 24 waves/CU (same as the previous best's 24.5 — R3/R4 showed dropping
// below ~12 w/CU regresses). Block owns 32 consecutive float4 positions.
// lane = t&31 (f4 position), cgrp = t>>5 (16 groups x 16 channels).
// Wave load = 2 x 512 B contiguous segments per instruction (vs 4 x 256 B
// before) — bigger segments, same 1 KiB/instruction.
// ---------------------------------------------------------------------------
__global__ __launch_bounds__(512, 6) void sa_reduce_kernel(
    const float* __restrict__ x, float* __restrict__ pool) {
  const int t = threadIdx.x;
  const int lane = t & 31;
  const int cgrp = t >> 5;                   // 0..15
  const unsigned if4 = (unsigned)blockIdx.x * CHUNKF4_ + lane;  // < 25088
  const unsigned bimg = if4 / HW4_;          // magic-mul (per-lane: handles
  const unsigned hw4 = if4 % HW4_;           // image-straddling chunks)
  const f4v* __restrict__ x4 = (const f4v*)x;
  const unsigned base = (bimg * C_ + cgrp * 16) * HW4_ + hw4;

  f4v s = {0.f, 0.f, 0.f, 0.f};
  f4v m = {-INFINITY, -INFINITY, -INFINITY, -INFINITY};
#pragma unroll 8
  for (int k = 0; k < 16; ++k) {             // c = cgrp*16 + k
    f4v v = x4[base + (unsigned)k * HW4_];
    s += v;
    m = (f4v){fmaxf(m.x, v.x), fmaxf(m.y, v.y),
              fmaxf(m.z, v.z), fmaxf(m.w, v.w)};
  }

  __shared__ f4v ssum[16][32];
  __shared__ f4v smax[16][32];
  ssum[cgrp][lane] = s;
  smax[cgrp][lane] = m;
  __syncthreads();

  if (t < 32) {
    f4v S = ssum[0][t];
    f4v M = smax[0][t];
#pragma unroll
    for (int g = 1; g < 16; ++g) {
      f4v sg = ssum[g][t];
      f4v mg = smax[g][t];
      S += sg;
      M = (f4v){fmaxf(M.x, mg.x), fmaxf(M.y, mg.y),
                fmaxf(M.z, mg.z), fmaxf(M.w, mg.w)};
    }
    f4v* p4 = (f4v*)pool;
    const unsigned jf4 = (unsigned)blockIdx.x * CHUNKF4_ + t;
    const unsigned bb = jf4 / HW4_;
    const unsigned hh = jf4 % HW4_;
    p4[bb * 2 * HW4_ + hh]        = S * (1.0f / (float)C_);  // avg plane
    p4[bb * 2 * HW4_ + HW4_ + hh] = M;                       // max plane
  }
}

// ---------------------------------------------------------------------------
// Kernel 2: fused 7x7 SAME conv (2->1) + sigmoid (LDS gate) + broadcast apply.
// 784 blocks x 512 threads; block owns 128 consecutive gate positions.
// Phase A: ALL 512 threads = 128 positions x {2 input channels x 2 kh-halves};
//   49-tap partials from pool (L1/L2-resident slice, ~4 KB/block) summed via
//   LDS -> sigmoid -> sgate4 LDS. Gate never touches HBM. 4-way split halves
//   the serial conv latency in front of the streaming phase.
// Phase B: lane = t&31, cgrp = t>>5; each thread applies the gate to 16
//   channels with 512 B-segment float4 loads (x L3-warm from K1) + NT stores
//   (NT keeps x resident in L3 instead of being evicted by the out stream).
// ---------------------------------------------------------------------------
__global__ __launch_bounds__(512, 6) void sa_conv_apply_kernel(
    const float* __restrict__ x, const float* __restrict__ pool,
    const float* __restrict__ wt, float* __restrict__ out) {
  const int t = threadIdx.x;
  __shared__ float partial[512];
  __shared__ f4v sgate4[CHUNKF4_];  // 128 gate floats

  // ---- Phase A: conv + sigmoid into LDS ----
  {
    const int pos = t >> 2;        // 0..127
    const int sub = t & 3;
    const int ic = sub & 1;
    const int khalf = sub >> 1;    // 0: kh 0..3, 1: kh 4..6
    const unsigned p = (unsigned)blockIdx.x * POSPB_ + (unsigned)pos;
    const unsigned bimg_a = p / HW_;
    const unsigned hw = p % HW_;
    const int h = (int)(hw / W_);
    const int w = (int)(hw % W_);
    const float* pl = pool + ((long)bimg_a * 2 + ic) * HW_;
    const float* wr0 = wt + ic * 49;
    const int kh0 = khalf ? 4 : 0;
    const int kh1 = khalf ? 7 : 4;
    float acc = 0.f;
    for (int kh = kh0; kh < kh1; ++kh) {
      const int ih = h + kh - 3;
      if (ih < 0 || ih >= H_) continue;
      const float* row = pl + ih * W_;
      const float* wr = wr0 + kh * 7;
#pragma unroll
      for (int kw = 0; kw < 7; ++kw) {
        const int iw = w + kw - 3;
        if (iw < 0 || iw >= W_) continue;
        acc = fmaf(row[iw], wr[kw], acc);
      }
    }
    partial[t] = acc;
  }
  __syncthreads();
  if (t < POSPB_) {
    float a = partial[4 * t] + partial[4 * t + 1] +
              partial[4 * t + 2] + partial[4 * t + 3];
    ((float*)sgate4)[t] = 1.0f / (1.0f + __expf(-a));
  }
  __syncthreads();

  // ---- Phase B: out = x * gate over 256 channels ----
  const int lane = t & 31;
  const int cgrp = t >> 5;                   // 0..15
  const unsigned if4 = (unsigned)blockIdx.x * CHUNKF4_ + lane;
  const unsigned bimg = if4 / HW4_;
  const unsigned hw4 = if4 % HW4_;
  const unsigned base = (bimg * C_ + cgrp * 16) * HW4_ + hw4;
  const f4v* __restrict__ x4 = (const f4v*)x;
  f4v* __restrict__ o4 = (f4v*)out;
  const f4v g = sgate4[lane];
#pragma unroll 8
  for (int k = 0; k < 16; ++k) {             // c = cgrp*16 + k
    const unsigned idx = base + (unsigned)k * HW4_;
    f4v v = x4[idx];
    __builtin_nontemporal_store(v * g, &o4[idx]);
  }
}

extern "C" void kernel_launch(void* const* d_in, const int* in_sizes, int n_in,
                              void* d_out, int out_size, void* d_ws, size_t ws_size,
                              hipStream_t stream) {
  const float* x  = (const float*)d_in[0];   // [32,256,56,56]
  const float* wc = (const float*)d_in[1];   // [1,2,7,7]
  float* out = (float*)d_out;
  float* pool = (float*)d_ws;                // [B,2,HW] = 802,816 B

  sa_reduce_kernel<<<GRID_, 512, 0, stream>>>(x, pool);
  sa_conv_apply_kernel<<<GRID_, 512, 0, stream>>>(x, pool, wc, out);
}